// Round 4
// baseline (224.208 us; speedup 1.0000x reference)
//
#include <hip/hip_runtime.h>
#include <cstddef>

#define Bsz 16
#define Nn  8
#define Ll  64
#define Ss  32
#define Dd  256
#define Hh  128

#define LOG2E 1.4426950408889634f

__device__ __forceinline__ float rcp_f(float x)  { return __builtin_amdgcn_rcpf(x); }
__device__ __forceinline__ float exp2_f(float x) { return __builtin_amdgcn_exp2f(x); }

__device__ __forceinline__ float fast_tanh(float x) {
    return 1.0f - 2.0f * rcp_f(exp2_f(x * (2.0f * LOG2E)) + 1.0f);
}
__device__ __forceinline__ float fast_sigmoid(float x) {
    return rcp_f(1.0f + exp2_f(-x * LOG2E));
}
__device__ __forceinline__ float wave_sum(float x) {
#pragma unroll
    for (int off = 32; off > 0; off >>= 1) x += __shfl_xor(x, off, 64);
    return x;
}
__device__ __forceinline__ float wave_max(float x) {
#pragma unroll
    for (int off = 32; off > 0; off >>= 1) x = fmaxf(x, __shfl_xor(x, off, 64));
    return x;
}

// ================= TN-form fp32 GEMM tile: C(128x64) = oscale * A(128xK) . B(64xK)^T ========
// A, B row-major with K=256 contiguous (native layout of x@W^T — no transpose needed).
// 256 threads. microtile 8(M)x4(N), strided assignment rows {ty+16i}, cols {tx+16j}.
__device__ __forceinline__ void gemm_tile_128x64(const float* __restrict__ A,  // pre-offset to m0
                                                 const float* __restrict__ B,  // pre-offset to n0
                                                 float* __restrict__ C,        // pre-offset (m0,col0)
                                                 int ldc, float oscale,
                                                 float (* __restrict__ As)[44],
                                                 float (* __restrict__ Bs)[44])
{
    const int tid = threadIdx.x;
    const int kq = tid & 7;        // k-float4 within 32-wide K tile
    const int mr = tid >> 3;       // 0..31
    const int tx = tid & 15;       // n
    const int ty = tid >> 4;       // m
    float acc[8][4] = {};
    for (int kc = 0; kc < 256; kc += 32) {
#pragma unroll
        for (int p = 0; p < 4; ++p) {
            float4 t = *(const float4*)&A[(size_t)(mr + 32 * p) * 256 + kc + kq * 4];
            *(float4*)&As[mr + 32 * p][kq * 4] = t;
        }
#pragma unroll
        for (int p = 0; p < 2; ++p) {
            float4 t = *(const float4*)&B[(size_t)(mr + 32 * p) * 256 + kc + kq * 4];
            *(float4*)&Bs[mr + 32 * p][kq * 4] = t;
        }
        __syncthreads();
#pragma unroll
        for (int kk = 0; kk < 32; kk += 4) {
            float4 br[4];
#pragma unroll
            for (int j = 0; j < 4; ++j) br[j] = *(const float4*)&Bs[tx + 16 * j][kk];
#pragma unroll
            for (int i = 0; i < 8; ++i) {
                float4 a = *(const float4*)&As[ty + 16 * i][kk];
#pragma unroll
                for (int j = 0; j < 4; ++j) {
                    acc[i][j] = fmaf(a.x, br[j].x, acc[i][j]);
                    acc[i][j] = fmaf(a.y, br[j].y, acc[i][j]);
                    acc[i][j] = fmaf(a.z, br[j].z, acc[i][j]);
                    acc[i][j] = fmaf(a.w, br[j].w, acc[i][j]);
                }
            }
        }
        __syncthreads();
    }
#pragma unroll
    for (int i = 0; i < 8; ++i)
#pragma unroll
        for (int j = 0; j < 4; ++j)
            C[(size_t)(ty + 16 * i) * ldc + tx + 16 * j] = acc[i][j] * oscale;
}

// blocks 0..255: Wx = C2 * x.W^T (M=8192); blocks 256..271: Us = C2 * s.U^T (M=512)
__global__ __launch_bounds__(256) void gemm_stage1(const float* __restrict__ x,
                                                   const float* __restrict__ s,
                                                   const float* __restrict__ W,
                                                   const float* __restrict__ U,
                                                   float* __restrict__ Wx,
                                                   float* __restrict__ Us)
{
    __shared__ float As[128][44];
    __shared__ float Bs[64][44];
    int blk = blockIdx.x;
    const float *Ap, *Bp; float* Cp;
    if (blk < 256) {
        int my = blk >> 2, nx = blk & 3;
        Ap = x + (size_t)my * 128 * 256;
        Bp = W + (size_t)nx * 64 * 256;
        Cp = Wx + (size_t)my * 128 * 256 + nx * 64;
    } else {
        int b2 = blk - 256;
        int my = b2 >> 2, nx = b2 & 3;
        Ap = s + (size_t)my * 128 * 256;
        Bp = U + (size_t)nx * 64 * 256;
        Cp = Us + (size_t)my * 128 * 256 + nx * 64;
    }
    gemm_tile_128x64(Ap, Bp, Cp, 256, 2.0f * LOG2E, As, Bs);
}

// ---------------- fused scores + softmax(L) + mean_s + sr ----------------
// 128 blocks (one per bn) x 512 threads (8 waves, 4 s each).
// Wx/Us arrive PRE-SCALED by 2*log2e. score = vsum - 2*sum_d v_d*rcp(exp2(wx+us)+1).
// Then a stays in LDS -> abar = mean_s a -> sr[b][n][d] = sum_l abar[l]*x[bn,l,d].
__global__ __launch_bounds__(512, 1) void scores_sr_kernel(const float* __restrict__ Wx,
                                                           const float* __restrict__ Us,
                                                           const float* __restrict__ v,
                                                           const float* __restrict__ x,
                                                           float* __restrict__ sr_out)
{
    __shared__ float wx[64][260];
    __shared__ float us[32][256];
    __shared__ float sc[32][64];
    __shared__ float abar[64];
    __shared__ float red[256];
    const int bn = blockIdx.x;
    const int b = bn >> 3, n = bn & 7;
    const int tid = threadIdx.x;
    const int lane = tid & 63, w = tid >> 6;
    {
        const float* wxg = Wx + (size_t)bn * (Ll * Dd);
        int c = tid & 63, r0 = tid >> 6;
#pragma unroll
        for (int p = 0; p < 8; ++p) {
            int r = r0 + p * 8;
            *(float4*)&wx[r][c * 4] = *(const float4*)&wxg[r * 256 + c * 4];
        }
        const float* usg = Us + (size_t)b * Ss * 256;
#pragma unroll
        for (int p = 0; p < 4; ++p) {
            int r = r0 + p * 8;
            *(float4*)&us[r][c * 4] = *(const float4*)&usg[r * 256 + c * 4];
        }
    }
    __syncthreads();
    float4 v4 = *(const float4*)&v[lane * 4];
    float vsum = wave_sum(v4.x + v4.y + v4.z + v4.w);
    const int s0 = w * 4;
    float4 u0 = *(const float4*)&us[s0 + 0][lane * 4];
    float4 u1 = *(const float4*)&us[s0 + 1][lane * 4];
    float4 u2 = *(const float4*)&us[s0 + 2][lane * 4];
    float4 u3 = *(const float4*)&us[s0 + 3][lane * 4];
    for (int l = 0; l < 64; ++l) {
        float4 wv = *(const float4*)&wx[l][lane * 4];
        float a0 =       v4.x * rcp_f(exp2_f(wv.x + u0.x) + 1.0f);
        a0 = fmaf(v4.y, rcp_f(exp2_f(wv.y + u0.y) + 1.0f), a0);
        a0 = fmaf(v4.z, rcp_f(exp2_f(wv.z + u0.z) + 1.0f), a0);
        a0 = fmaf(v4.w, rcp_f(exp2_f(wv.w + u0.w) + 1.0f), a0);
        float a1 =       v4.x * rcp_f(exp2_f(wv.x + u1.x) + 1.0f);
        a1 = fmaf(v4.y, rcp_f(exp2_f(wv.y + u1.y) + 1.0f), a1);
        a1 = fmaf(v4.z, rcp_f(exp2_f(wv.z + u1.z) + 1.0f), a1);
        a1 = fmaf(v4.w, rcp_f(exp2_f(wv.w + u1.w) + 1.0f), a1);
        float a2 =       v4.x * rcp_f(exp2_f(wv.x + u2.x) + 1.0f);
        a2 = fmaf(v4.y, rcp_f(exp2_f(wv.y + u2.y) + 1.0f), a2);
        a2 = fmaf(v4.z, rcp_f(exp2_f(wv.z + u2.z) + 1.0f), a2);
        a2 = fmaf(v4.w, rcp_f(exp2_f(wv.w + u2.w) + 1.0f), a2);
        float a3 =       v4.x * rcp_f(exp2_f(wv.x + u3.x) + 1.0f);
        a3 = fmaf(v4.y, rcp_f(exp2_f(wv.y + u3.y) + 1.0f), a3);
        a3 = fmaf(v4.z, rcp_f(exp2_f(wv.z + u3.z) + 1.0f), a3);
        a3 = fmaf(v4.w, rcp_f(exp2_f(wv.w + u3.w) + 1.0f), a3);
        a0 = wave_sum(a0); a1 = wave_sum(a1); a2 = wave_sum(a2); a3 = wave_sum(a3);
        if (lane == 0) {
            sc[s0 + 0][l] = vsum - 2.0f * a0;
            sc[s0 + 1][l] = vsum - 2.0f * a1;
            sc[s0 + 2][l] = vsum - 2.0f * a2;
            sc[s0 + 3][l] = vsum - 2.0f * a3;
        }
    }
    __syncthreads();
    // softmax over l for this wave's 4 s; normalized a written back into sc
#pragma unroll
    for (int j = 0; j < 4; ++j) {
        float sv = sc[s0 + j][lane];
        float e = exp2_f((sv - wave_max(sv)) * LOG2E);
        float inv = rcp_f(wave_sum(e));
        sc[s0 + j][lane] = e * inv;
    }
    __syncthreads();
    if (tid < 64) {
        float acc = 0.f;
#pragma unroll
        for (int s = 0; s < 32; ++s) acc += sc[s][tid];
        abar[tid] = acc * (1.0f / 32.0f);
    }
    __syncthreads();
    // sr: 512 threads = (half, d). half covers 32 l's.
    {
        int d = tid & 255, half = tid >> 8;
        const float* xp = x + (size_t)bn * Ll * Dd;
        float acc = 0.f;
#pragma unroll 8
        for (int l = half * 32; l < half * 32 + 32; ++l)
            acc = fmaf(abar[l], xp[l * Dd + d], acc);
        if (half == 1) red[d] = acc;
        __syncthreads();
        if (half == 0)
            sr_out[((size_t)b * Nn + n) * Dd + d] = acc + red[d];
    }
}

// ---------------- fused gx-GEMM + sequential BiLSTM ----------------
// 32 blocks (dir*16+b) x 512 threads. sr slice [8][256] staged in LDS; thread g
// computes its own gate preactivations for all 8 steps (time-ordered regs), then
// the sequential recurrence with Whh row g held in VGPRs.
__global__ __launch_bounds__(512) void lstm_fused(const float* __restrict__ sr,
                                                  const float* __restrict__ Wih_f,
                                                  const float* __restrict__ Wih_b,
                                                  const float* __restrict__ Whh_f,
                                                  const float* __restrict__ Whh_b,
                                                  const float* __restrict__ bih_f, const float* __restrict__ bhh_f,
                                                  const float* __restrict__ bih_b, const float* __restrict__ bhh_b,
                                                  float* __restrict__ h_out)
{
    int blk = blockIdx.x;
    int dir = blk >> 4, b = blk & 15;
    int g = threadIdx.x;
    __shared__ float s_lds[8][256];
    __shared__ float h[128], c[128], gb[512];
    {   // stage sr[b]: 8x256 contiguous
        int nr = g >> 6, off = (g & 63) * 4;
        *(float4*)&s_lds[nr][off] = *(const float4*)&sr[((size_t)b * Nn + nr) * Dd + off];
        if (g < 128) { h[g] = 0.f; c[g] = 0.f; }
    }
    __syncthreads();
    // gate preactivations in TIME order (compile-time index in recurrence loop)
    const float* wih = ((dir == 0) ? Wih_f : Wih_b) + (size_t)g * 256;
    const float* srow[8];
#pragma unroll
    for (int tt = 0; tt < 8; ++tt) srow[tt] = s_lds[dir ? 7 - tt : tt];
    float gpre[8] = {};
#pragma unroll
    for (int kq = 0; kq < 64; ++kq) {
        float4 wv = ((const float4*)wih)[kq];
#pragma unroll
        for (int tt = 0; tt < 8; ++tt) {
            const float4 sv = *(const float4*)&srow[tt][kq * 4];
            gpre[tt] = fmaf(wv.x, sv.x, gpre[tt]);
            gpre[tt] = fmaf(wv.y, sv.y, gpre[tt]);
            gpre[tt] = fmaf(wv.z, sv.z, gpre[tt]);
            gpre[tt] = fmaf(wv.w, sv.w, gpre[tt]);
        }
    }
    const float* wr = ((dir == 0) ? Whh_f : Whh_b) + (size_t)g * 128;
    float4 w4[32];
#pragma unroll
    for (int k = 0; k < 32; ++k) w4[k] = ((const float4*)wr)[k];
    float bias = (dir == 0) ? (bih_f[g] + bhh_f[g]) : (bih_b[g] + bhh_b[g]);
    __syncthreads();
#pragma unroll
    for (int t = 0; t < Nn; ++t) {
        float a0 = gpre[t] + bias;
        float a1 = 0.f, a2 = 0.f, a3 = 0.f;
#pragma unroll
        for (int k = 0; k < 32; ++k) {
            float4 hv = *(const float4*)&h[k * 4];
            a0 = fmaf(w4[k].x, hv.x, a0);
            a1 = fmaf(w4[k].y, hv.y, a1);
            a2 = fmaf(w4[k].z, hv.z, a2);
            a3 = fmaf(w4[k].w, hv.w, a3);
        }
        float pre = (a0 + a1) + (a2 + a3);
        float act = (g < 256 || g >= 384) ? fast_sigmoid(pre) : fast_tanh(pre);
        gb[g] = act;
        __syncthreads();
        if (g < 128) {
            float i_ = gb[g], f_ = gb[128 + g], g_ = gb[256 + g], o_ = gb[384 + g];
            float cn = fmaf(f_, c[g], i_ * g_);
            float hn = o_ * fast_tanh(cn);
            c[g] = cn; h[g] = hn;
            int n = dir ? (7 - t) : t;
            h_out[(((size_t)dir * Nn + n) * Bsz + b) * Hh + g] = hn;
        }
        __syncthreads();
    }
}

// ---------------- fused self-attention scores + softmax + pool ----------------
__global__ __launch_bounds__(256) void attpool_kernel(const float* __restrict__ hbuf,
                                                      const float* __restrict__ saW,
                                                      const float* __restrict__ sab,
                                                      const float* __restrict__ sav,
                                                      float* __restrict__ out)
{
    int b = blockIdx.x;
    int e = threadIdx.x;
    __shared__ float cvec[8][260];
    __shared__ float part[8][4];
#pragma unroll
    for (int n = 0; n < 8; ++n)
        cvec[n][e] = (e < 128) ? hbuf[((size_t)n * Bsz + b) * Hh + e]
                               : hbuf[((size_t)(Nn + n) * Bsz + b) * Hh + (e - 128)];
    __syncthreads();
    const float* wrow = saW + (size_t)e * 256;
    float acc[8];
    float b0 = sab[e];
#pragma unroll
    for (int n = 0; n < 8; ++n) acc[n] = b0;
#pragma unroll 2
    for (int dq0 = 0; dq0 < 8; ++dq0) {
        float4 wq[8];
#pragma unroll
        for (int q = 0; q < 8; ++q) wq[q] = *(const float4*)&wrow[dq0 * 32 + q * 4];
#pragma unroll
        for (int q = 0; q < 8; ++q) {
#pragma unroll
            for (int n = 0; n < 8; ++n) {
                float4 cv = *(const float4*)&cvec[n][dq0 * 32 + q * 4];
                acc[n] = fmaf(wq[q].x, cv.x, acc[n]);
                acc[n] = fmaf(wq[q].y, cv.y, acc[n]);
                acc[n] = fmaf(wq[q].z, cv.z, acc[n]);
                acc[n] = fmaf(wq[q].w, cv.w, acc[n]);
            }
        }
    }
    int w = e >> 6, lane = e & 63;
    float se = sav[e];
#pragma unroll
    for (int n = 0; n < 8; ++n) {
        float t = fast_tanh(acc[n]) * se;
        t = wave_sum(t);
        if (lane == 0) part[n][w] = t;
    }
    __syncthreads();
    float av[8], mx = -1e30f;
#pragma unroll
    for (int n = 0; n < 8; ++n) {
        av[n] = part[n][0] + part[n][1] + part[n][2] + part[n][3];
        mx = fmaxf(mx, av[n]);
    }
    float sum = 0.f;
#pragma unroll
    for (int n = 0; n < 8; ++n) { av[n] = exp2_f((av[n] - mx) * LOG2E); sum += av[n]; }
    float inv = rcp_f(sum);
    float acco = 0.f;
#pragma unroll
    for (int n = 0; n < 8; ++n) acco = fmaf(av[n], cvec[n][e], acco);
    out[b * 256 + e] = acco * inv;
}

extern "C" void kernel_launch(void* const* d_in, const int* in_sizes, int n_in,
                              void* d_out, int out_size, void* d_ws, size_t ws_size,
                              hipStream_t stream) {
    const float* x     = (const float*)d_in[0];
    const float* s     = (const float*)d_in[1];
    const float* W     = (const float*)d_in[2];
    const float* U     = (const float*)d_in[3];
    const float* v     = (const float*)d_in[4];
    const float* Wih_f = (const float*)d_in[5];
    const float* Whh_f = (const float*)d_in[6];
    const float* bih_f = (const float*)d_in[7];
    const float* bhh_f = (const float*)d_in[8];
    const float* Wih_b = (const float*)d_in[9];
    const float* Whh_b = (const float*)d_in[10];
    const float* bih_b = (const float*)d_in[11];
    const float* bhh_b = (const float*)d_in[12];
    const float* saW   = (const float*)d_in[13];
    const float* sab   = (const float*)d_in[14];
    const float* sav   = (const float*)d_in[15];
    float* out = (float*)d_out;
    float* ws  = (float*)d_ws;

    float* Wx    = ws;                 // 2097152
    float* Us    = Wx + 2097152;       // 131072
    float* sr_nb = Us + 131072;        // 32768  [b][n][256]
    float* hbuf  = sr_nb + 32768;      // 32768

    hipLaunchKernelGGL(gemm_stage1, dim3(272), dim3(256), 0, stream, x, s, W, U, Wx, Us);
    hipLaunchKernelGGL(scores_sr_kernel, dim3(128), dim3(512), 0, stream, Wx, Us, v, x, sr_nb);
    hipLaunchKernelGGL(lstm_fused, dim3(32), dim3(512), 0, stream,
                       sr_nb, Wih_f, Wih_b, Whh_f, Whh_b,
                       bih_f, bhh_f, bih_b, bhh_b, hbuf);
    hipLaunchKernelGGL(attpool_kernel, dim3(16), dim3(256), 0, stream, hbuf, saW, sab, sav, out);
}

// Round 5
// 190.071 us; speedup vs baseline: 1.1796x; 1.1796x over previous
//
#include <hip/hip_runtime.h>
#include <cstddef>

#define Bsz 16
#define Nn  8
#define Ll  64
#define Ss  32
#define Dd  256
#define Hh  128

#define LOG2E 1.4426950408889634f

__device__ __forceinline__ float rcp_f(float x)  { return __builtin_amdgcn_rcpf(x); }
__device__ __forceinline__ float exp2_f(float x) { return __builtin_amdgcn_exp2f(x); }

__device__ __forceinline__ float fast_tanh(float x) {
    return 1.0f - 2.0f * rcp_f(exp2_f(x * (2.0f * LOG2E)) + 1.0f);
}
__device__ __forceinline__ float fast_sigmoid(float x) {
    return rcp_f(1.0f + exp2_f(-x * LOG2E));
}
__device__ __forceinline__ float wave_sum(float x) {
#pragma unroll
    for (int off = 32; off > 0; off >>= 1) x += __shfl_xor(x, off, 64);
    return x;
}
__device__ __forceinline__ float wave_max(float x) {
#pragma unroll
    for (int off = 32; off > 0; off >>= 1) x = fmaxf(x, __shfl_xor(x, off, 64));
    return x;
}

// ================= TN-form fp32 GEMM tile: C(128x64) = exp2(C2 * A.B^T) =================
// A, B row-major with K=256 contiguous. 256 threads, microtile 8x4 strided.
// Epilogue applies exp2(C2*acc): output feeds the folded-tanh scores kernel.
__device__ __forceinline__ void gemm_tile_128x64_exp(const float* __restrict__ A,
                                                     const float* __restrict__ B,
                                                     float* __restrict__ C, int ldc,
                                                     float (* __restrict__ As)[44],
                                                     float (* __restrict__ Bs)[44])
{
    const int tid = threadIdx.x;
    const int kq = tid & 7;
    const int mr = tid >> 3;
    const int tx = tid & 15;
    const int ty = tid >> 4;
    float acc[8][4] = {};
    for (int kc = 0; kc < 256; kc += 32) {
#pragma unroll
        for (int p = 0; p < 4; ++p) {
            float4 t = *(const float4*)&A[(size_t)(mr + 32 * p) * 256 + kc + kq * 4];
            *(float4*)&As[mr + 32 * p][kq * 4] = t;
        }
#pragma unroll
        for (int p = 0; p < 2; ++p) {
            float4 t = *(const float4*)&B[(size_t)(mr + 32 * p) * 256 + kc + kq * 4];
            *(float4*)&Bs[mr + 32 * p][kq * 4] = t;
        }
        __syncthreads();
#pragma unroll
        for (int kk = 0; kk < 32; kk += 4) {
            float4 br[4];
#pragma unroll
            for (int j = 0; j < 4; ++j) br[j] = *(const float4*)&Bs[tx + 16 * j][kk];
#pragma unroll
            for (int i = 0; i < 8; ++i) {
                float4 a = *(const float4*)&As[ty + 16 * i][kk];
#pragma unroll
                for (int j = 0; j < 4; ++j) {
                    acc[i][j] = fmaf(a.x, br[j].x, acc[i][j]);
                    acc[i][j] = fmaf(a.y, br[j].y, acc[i][j]);
                    acc[i][j] = fmaf(a.z, br[j].z, acc[i][j]);
                    acc[i][j] = fmaf(a.w, br[j].w, acc[i][j]);
                }
            }
        }
        __syncthreads();
    }
    const float C2 = 2.0f * LOG2E;
#pragma unroll
    for (int i = 0; i < 8; ++i)
#pragma unroll
        for (int j = 0; j < 4; ++j)
            C[(size_t)(ty + 16 * i) * ldc + tx + 16 * j] = exp2_f(acc[i][j] * C2);
}

// blocks 0..255: eWx = exp2(C2*x.W^T); blocks 256..271: eUs = exp2(C2*s.U^T)
__global__ __launch_bounds__(256) void gemm_stage1(const float* __restrict__ x,
                                                   const float* __restrict__ s,
                                                   const float* __restrict__ W,
                                                   const float* __restrict__ U,
                                                   float* __restrict__ eWx,
                                                   float* __restrict__ eUs)
{
    __shared__ float As[128][44];
    __shared__ float Bs[64][44];
    int blk = blockIdx.x;
    const float *Ap, *Bp; float* Cp;
    if (blk < 256) {
        int my = blk >> 2, nx = blk & 3;
        Ap = x + (size_t)my * 128 * 256;
        Bp = W + (size_t)nx * 64 * 256;
        Cp = eWx + (size_t)my * 128 * 256 + nx * 64;
    } else {
        int b2 = blk - 256;
        int my = b2 >> 2, nx = b2 & 3;
        Ap = s + (size_t)my * 128 * 256;
        Bp = U + (size_t)nx * 64 * 256;
        Cp = eUs + (size_t)my * 128 * 256 + nx * 64;
    }
    gemm_tile_128x64_exp(Ap, Bp, Cp, 256, As, Bs);
}

// ---------------- scores + softmax(L) + partial mean_s ----------------
// 256 blocks = (bn, s-half). 512 threads = 8 waves; wave owns 2 s; LANE = l.
// tanh fold: contribution = v_d * rcp(fma(ewx, eus, 1)); logits = -2*acc
// (the vsum constant cancels in softmax). eus/v are wave-uniform -> SGPR loads.
__global__ __launch_bounds__(512, 1) void scores_kernel(const float* __restrict__ eWx,
                                                        const float* __restrict__ eUs,
                                                        const float* __restrict__ v,
                                                        float* __restrict__ pabar)
{
    __shared__ float ewx[64][260];
    __shared__ float red[8][64];
    const int bid = blockIdx.x;
    const int bn = bid >> 1, sh = bid & 1;
    const int b = bid >> 4;
    const int tid = threadIdx.x;
    const int lane = tid & 63;                                   // = l
    const int w = __builtin_amdgcn_readfirstlane(tid >> 6);      // wave id (uniform)
    {   // stage ewx[64][256] (coalesced, uniform 8 req/bank on write)
        const float* wxg = eWx + (size_t)bn * (Ll * Dd);
        int c = tid & 63, r0 = tid >> 6;
#pragma unroll
        for (int p = 0; p < 8; ++p) {
            int r = r0 + p * 8;
            *(float4*)&ewx[r][c * 4] = *(const float4*)&wxg[r * 256 + c * 4];
        }
    }
    __syncthreads();
    const int s0 = sh * 16 + w * 2;
    const float* eu0 = eUs + ((size_t)b * Ss + s0) * 256;        // uniform pointers
    const float* eu1 = eu0 + 256;
    float acc0 = 0.f, acc1 = 0.f;
#pragma unroll 8
    for (int q = 0; q < 64; ++q) {
        float4 w4 = *(const float4*)&ewx[lane][q * 4];           // ds_read_b128
        float4 e0 = *(const float4*)&eu0[q * 4];                 // s_load (uniform)
        float4 e1 = *(const float4*)&eu1[q * 4];
        float4 vv = *(const float4*)&v[q * 4];
        acc0 = fmaf(vv.x, rcp_f(fmaf(w4.x, e0.x, 1.0f)), acc0);
        acc0 = fmaf(vv.y, rcp_f(fmaf(w4.y, e0.y, 1.0f)), acc0);
        acc0 = fmaf(vv.z, rcp_f(fmaf(w4.z, e0.z, 1.0f)), acc0);
        acc0 = fmaf(vv.w, rcp_f(fmaf(w4.w, e0.w, 1.0f)), acc0);
        acc1 = fmaf(vv.x, rcp_f(fmaf(w4.x, e1.x, 1.0f)), acc1);
        acc1 = fmaf(vv.y, rcp_f(fmaf(w4.y, e1.y, 1.0f)), acc1);
        acc1 = fmaf(vv.z, rcp_f(fmaf(w4.z, e1.z, 1.0f)), acc1);
        acc1 = fmaf(vv.w, rcp_f(fmaf(w4.w, e1.w, 1.0f)), acc1);
    }
    // logits (lane = l); softmax over lanes, no LDS
    float t0 = -2.0f * acc0, t1 = -2.0f * acc1;
    float e0 = exp2_f((t0 - wave_max(t0)) * LOG2E);
    float e1 = exp2_f((t1 - wave_max(t1)) * LOG2E);
    float a0 = e0 * rcp_f(wave_sum(e0));
    float a1 = e1 * rcp_f(wave_sum(e1));
    red[w][lane] = a0 + a1;
    __syncthreads();
    if (tid < 64) {
        float p = 0.f;
#pragma unroll
        for (int k = 0; k < 8; ++k) p += red[k][tid];
        pabar[(size_t)bid * 64 + tid] = p;   // partial sum over 16 s
    }
}

// ---------------- abar combine + sr[b][n][d] = sum_l abar[l]*x[bn,l,d] ----------------
__global__ __launch_bounds__(256) void sr_kernel(const float* __restrict__ pabar,
                                                 const float* __restrict__ x,
                                                 float* __restrict__ sr_out)
{
    int bn = blockIdx.x;
    int tid = threadIdx.x;
    __shared__ float abar[64];
    if (tid < 64)
        abar[tid] = (pabar[(size_t)(bn * 2) * 64 + tid] +
                     pabar[(size_t)(bn * 2 + 1) * 64 + tid]) * (1.0f / 32.0f);
    __syncthreads();
    const float* xp = x + (size_t)bn * Ll * Dd;
    float acc = 0.f;
#pragma unroll 8
    for (int l = 0; l < Ll; ++l)
        acc = fmaf(abar[l], xp[l * Dd + tid], acc);
    sr_out[(size_t)bn * Dd + tid] = acc;     // [b][n][d] since bn = b*8+n
}

// ---------------- fused gx-GEMM + sequential BiLSTM ----------------
__global__ __launch_bounds__(512) void lstm_fused(const float* __restrict__ sr,
                                                  const float* __restrict__ Wih_f,
                                                  const float* __restrict__ Wih_b,
                                                  const float* __restrict__ Whh_f,
                                                  const float* __restrict__ Whh_b,
                                                  const float* __restrict__ bih_f, const float* __restrict__ bhh_f,
                                                  const float* __restrict__ bih_b, const float* __restrict__ bhh_b,
                                                  float* __restrict__ h_out)
{
    int blk = blockIdx.x;
    int dir = blk >> 4, b = blk & 15;
    int g = threadIdx.x;
    __shared__ float s_lds[8][256];
    __shared__ float h[128], c[128], gb[512];
    {
        int nr = g >> 6, off = (g & 63) * 4;
        *(float4*)&s_lds[nr][off] = *(const float4*)&sr[((size_t)b * Nn + nr) * Dd + off];
        if (g < 128) { h[g] = 0.f; c[g] = 0.f; }
    }
    __syncthreads();
    const float* wih = ((dir == 0) ? Wih_f : Wih_b) + (size_t)g * 256;
    const float* srow[8];
#pragma unroll
    for (int tt = 0; tt < 8; ++tt) srow[tt] = s_lds[dir ? 7 - tt : tt];
    float gpre[8] = {};
#pragma unroll
    for (int kq = 0; kq < 64; ++kq) {
        float4 wv = ((const float4*)wih)[kq];
#pragma unroll
        for (int tt = 0; tt < 8; ++tt) {
            const float4 sv = *(const float4*)&srow[tt][kq * 4];
            gpre[tt] = fmaf(wv.x, sv.x, gpre[tt]);
            gpre[tt] = fmaf(wv.y, sv.y, gpre[tt]);
            gpre[tt] = fmaf(wv.z, sv.z, gpre[tt]);
            gpre[tt] = fmaf(wv.w, sv.w, gpre[tt]);
        }
    }
    const float* wr = ((dir == 0) ? Whh_f : Whh_b) + (size_t)g * 128;
    float4 w4[32];
#pragma unroll
    for (int k = 0; k < 32; ++k) w4[k] = ((const float4*)wr)[k];
    float bias = (dir == 0) ? (bih_f[g] + bhh_f[g]) : (bih_b[g] + bhh_b[g]);
    __syncthreads();
#pragma unroll
    for (int t = 0; t < Nn; ++t) {
        float a0 = gpre[t] + bias;
        float a1 = 0.f, a2 = 0.f, a3 = 0.f;
#pragma unroll
        for (int k = 0; k < 32; ++k) {
            float4 hv = *(const float4*)&h[k * 4];
            a0 = fmaf(w4[k].x, hv.x, a0);
            a1 = fmaf(w4[k].y, hv.y, a1);
            a2 = fmaf(w4[k].z, hv.z, a2);
            a3 = fmaf(w4[k].w, hv.w, a3);
        }
        float pre = (a0 + a1) + (a2 + a3);
        float act = (g < 256 || g >= 384) ? fast_sigmoid(pre) : fast_tanh(pre);
        gb[g] = act;
        __syncthreads();
        if (g < 128) {
            float i_ = gb[g], f_ = gb[128 + g], g_ = gb[256 + g], o_ = gb[384 + g];
            float cn = fmaf(f_, c[g], i_ * g_);
            float hn = o_ * fast_tanh(cn);
            c[g] = cn; h[g] = hn;
            int n = dir ? (7 - t) : t;
            h_out[(((size_t)dir * Nn + n) * Bsz + b) * Hh + g] = hn;
        }
        __syncthreads();
    }
}

// ---------------- fused self-attention scores + softmax + pool ----------------
__global__ __launch_bounds__(256) void attpool_kernel(const float* __restrict__ hbuf,
                                                      const float* __restrict__ saW,
                                                      const float* __restrict__ sab,
                                                      const float* __restrict__ sav,
                                                      float* __restrict__ out)
{
    int b = blockIdx.x;
    int e = threadIdx.x;
    __shared__ float cvec[8][260];
    __shared__ float part[8][4];
#pragma unroll
    for (int n = 0; n < 8; ++n)
        cvec[n][e] = (e < 128) ? hbuf[((size_t)n * Bsz + b) * Hh + e]
                               : hbuf[((size_t)(Nn + n) * Bsz + b) * Hh + (e - 128)];
    __syncthreads();
    const float* wrow = saW + (size_t)e * 256;
    float acc[8];
    float b0 = sab[e];
#pragma unroll
    for (int n = 0; n < 8; ++n) acc[n] = b0;
#pragma unroll 2
    for (int dq0 = 0; dq0 < 8; ++dq0) {
        float4 wq[8];
#pragma unroll
        for (int q = 0; q < 8; ++q) wq[q] = *(const float4*)&wrow[dq0 * 32 + q * 4];
#pragma unroll
        for (int q = 0; q < 8; ++q) {
#pragma unroll
            for (int n = 0; n < 8; ++n) {
                float4 cv = *(const float4*)&cvec[n][dq0 * 32 + q * 4];
                acc[n] = fmaf(wq[q].x, cv.x, acc[n]);
                acc[n] = fmaf(wq[q].y, cv.y, acc[n]);
                acc[n] = fmaf(wq[q].z, cv.z, acc[n]);
                acc[n] = fmaf(wq[q].w, cv.w, acc[n]);
            }
        }
    }
    int w = e >> 6, lane = e & 63;
    float se = sav[e];
#pragma unroll
    for (int n = 0; n < 8; ++n) {
        float t = fast_tanh(acc[n]) * se;
        t = wave_sum(t);
        if (lane == 0) part[n][w] = t;
    }
    __syncthreads();
    float av[8], mx = -1e30f;
#pragma unroll
    for (int n = 0; n < 8; ++n) {
        av[n] = part[n][0] + part[n][1] + part[n][2] + part[n][3];
        mx = fmaxf(mx, av[n]);
    }
    float sum = 0.f;
#pragma unroll
    for (int n = 0; n < 8; ++n) { av[n] = exp2_f((av[n] - mx) * LOG2E); sum += av[n]; }
    float inv = rcp_f(sum);
    float acco = 0.f;
#pragma unroll
    for (int n = 0; n < 8; ++n) acco = fmaf(av[n], cvec[n][e], acco);
    out[b * 256 + e] = acco * inv;
}

extern "C" void kernel_launch(void* const* d_in, const int* in_sizes, int n_in,
                              void* d_out, int out_size, void* d_ws, size_t ws_size,
                              hipStream_t stream) {
    const float* x     = (const float*)d_in[0];
    const float* s     = (const float*)d_in[1];
    const float* W     = (const float*)d_in[2];
    const float* U     = (const float*)d_in[3];
    const float* v     = (const float*)d_in[4];
    const float* Wih_f = (const float*)d_in[5];
    const float* Whh_f = (const float*)d_in[6];
    const float* bih_f = (const float*)d_in[7];
    const float* bhh_f = (const float*)d_in[8];
    const float* Wih_b = (const float*)d_in[9];
    const float* Whh_b = (const float*)d_in[10];
    const float* bih_b = (const float*)d_in[11];
    const float* bhh_b = (const float*)d_in[12];
    const float* saW   = (const float*)d_in[13];
    const float* sab   = (const float*)d_in[14];
    const float* sav   = (const float*)d_in[15];
    float* out = (float*)d_out;
    float* ws  = (float*)d_ws;

    float* eWx   = ws;                 // 2097152
    float* eUs   = eWx + 2097152;      // 131072
    float* pabar = eUs + 131072;       // 256*64 = 16384
    float* sr_nb = pabar + 16384;      // 32768  [b][n][256]
    float* hbuf  = sr_nb + 32768;      // 32768

    hipLaunchKernelGGL(gemm_stage1, dim3(272), dim3(256), 0, stream, x, s, W, U, eWx, eUs);
    hipLaunchKernelGGL(scores_kernel, dim3(256), dim3(512), 0, stream, eWx, eUs, v, pabar);
    hipLaunchKernelGGL(sr_kernel, dim3(128), dim3(256), 0, stream, pabar, x, sr_nb);
    hipLaunchKernelGGL(lstm_fused, dim3(32), dim3(512), 0, stream,
                       sr_nb, Wih_f, Wih_b, Whh_f, Whh_b,
                       bih_f, bhh_f, bih_b, bhh_b, hbuf);
    hipLaunchKernelGGL(attpool_kernel, dim3(16), dim3(256), 0, stream, hbuf, saW, sab, sav, out);
}

// Round 6
// 173.416 us; speedup vs baseline: 1.2929x; 1.0960x over previous
//
#include <hip/hip_runtime.h>
#include <cstddef>

#define Bsz 16
#define Nn  8
#define Ll  64
#define Ss  32
#define Dd  256
#define Hh  128

#define LOG2E 1.4426950408889634f

typedef short bf16x8 __attribute__((ext_vector_type(8)));   // 8 bf16 = 4 VGPR
typedef float f32x4  __attribute__((ext_vector_type(4)));   // MFMA acc

__device__ __forceinline__ float rcp_f(float x)  { return __builtin_amdgcn_rcpf(x); }
__device__ __forceinline__ float exp2_f(float x) { return __builtin_amdgcn_exp2f(x); }

__device__ __forceinline__ float fast_tanh(float x) {
    return 1.0f - 2.0f * rcp_f(exp2_f(x * (2.0f * LOG2E)) + 1.0f);
}
__device__ __forceinline__ float fast_sigmoid(float x) {
    return rcp_f(1.0f + exp2_f(-x * LOG2E));
}
__device__ __forceinline__ float wave_sum(float x) {
#pragma unroll
    for (int off = 32; off > 0; off >>= 1) x += __shfl_xor(x, off, 64);
    return x;
}
__device__ __forceinline__ float wave_max(float x) {
#pragma unroll
    for (int off = 32; off > 0; off >>= 1) x = fmaxf(x, __shfl_xor(x, off, 64));
    return x;
}

// ---------------- bf16 hi/lo split (RNE); hi+lo represents f to ~2^-18 rel ----------------
__device__ __forceinline__ void bsplit(float f, unsigned short& h, unsigned short& l) {
    unsigned u  = __builtin_bit_cast(unsigned, f);
    unsigned hb = (u + 0x7FFFu + ((u >> 16) & 1u)) >> 16;
    float hf = __builtin_bit_cast(float, hb << 16);
    h = (unsigned short)hb;
    float r = f - hf;                                  // exact (Sterbenz)
    unsigned ur = __builtin_bit_cast(unsigned, r);
    l = (unsigned short)((ur + 0x7FFFu + ((ur >> 16) & 1u)) >> 16);
}

// ---------------- prepass: split x, s, W, U into hi/lo bf16 ----------------
// grid 2304 x 256; one float4 per thread.
__global__ __launch_bounds__(256) void split_bf16(
    const float* __restrict__ x, const float* __restrict__ s,
    const float* __restrict__ W, const float* __restrict__ U,
    unsigned short* __restrict__ xh, unsigned short* __restrict__ xl,
    unsigned short* __restrict__ sh2, unsigned short* __restrict__ sl2,
    unsigned short* __restrict__ Wh, unsigned short* __restrict__ Wl,
    unsigned short* __restrict__ Uh, unsigned short* __restrict__ Ul)
{
    int g = blockIdx.x * 256 + threadIdx.x;
    const float* src; unsigned short *dh, *dl; int e;
    if      (g < 524288) { src = x; dh = xh;  dl = xl;  e = g; }
    else if (g < 557056) { src = s; dh = sh2; dl = sl2; e = g - 524288; }
    else if (g < 573440) { src = W; dh = Wh;  dl = Wl;  e = g - 557056; }
    else                 { src = U; dh = Uh;  dl = Ul;  e = g - 573440; }
    float4 f = ((const float4*)src)[e];
    ushort4 h, l;
    bsplit(f.x, h.x, l.x);
    bsplit(f.y, h.y, l.y);
    bsplit(f.z, h.z, l.z);
    bsplit(f.w, h.w, l.w);
    ((ushort4*)dh)[e] = h;
    ((ushort4*)dl)[e] = l;
}

// ---------------- MFMA split-bf16 GEMM: C = exp2(C2 * A.B^T) ----------------
// A [M][256], B [256-rows][256] both K-contiguous (hi/lo bf16). Tile 128x128,
// 256 thr = 4 waves, wave = 64x64 via 4x4 mfma_f32_16x16x32_bf16 frags, K-step 32.
// Split-3: hi.hi + hi.lo + lo.hi (lo.lo ~2^-18, dropped).
// blocks 0..127: eWx (M=8192); 128..135: eUs (M=512).
__global__ __launch_bounds__(256) void gemm_mfma(
    const unsigned short* __restrict__ xh, const unsigned short* __restrict__ xl,
    const unsigned short* __restrict__ sh2, const unsigned short* __restrict__ sl2,
    const unsigned short* __restrict__ Wh, const unsigned short* __restrict__ Wl,
    const unsigned short* __restrict__ Uh, const unsigned short* __restrict__ Ul,
    float* __restrict__ eWx, float* __restrict__ eUs)
{
    __shared__ unsigned short Ah[128][40], Al[128][40], Bh[128][40], Bl[128][40];
    const int tid = threadIdx.x;
    int blk = blockIdx.x;
    const unsigned short *agh, *agl, *bgh, *bgl; float* C;
    if (blk < 128) {
        int my = blk >> 1, nxb = blk & 1;
        agh = xh + (size_t)my * 128 * 256;  agl = xl + (size_t)my * 128 * 256;
        bgh = Wh + (size_t)nxb * 128 * 256; bgl = Wl + (size_t)nxb * 128 * 256;
        C = eWx + (size_t)my * 128 * 256 + nxb * 128;
    } else {
        int b2 = blk - 128;
        int my = b2 >> 1, nxb = b2 & 1;
        agh = sh2 + (size_t)my * 128 * 256; agl = sl2 + (size_t)my * 128 * 256;
        bgh = Uh + (size_t)nxb * 128 * 256; bgl = Ul + (size_t)nxb * 128 * 256;
        C = eUs + (size_t)my * 128 * 256 + nxb * 128;
    }
    const int lane = tid & 63, w = tid >> 6;
    const int wm = (w & 1) * 64, wn = (w >> 1) * 64;
    const int fr = lane & 15, fk = (lane >> 4) * 8;
    f32x4 acc[4][4] = {};
    for (int kc = 0; kc < 256; kc += 32) {
#pragma unroll
        for (int p = 0; p < 2; ++p) {
            int idx = p * 256 + tid;
            int row = idx >> 2, ch = (idx & 3) * 8;
            *(uint4*)&Ah[row][ch] = *(const uint4*)&agh[(size_t)row * 256 + kc + ch];
            *(uint4*)&Al[row][ch] = *(const uint4*)&agl[(size_t)row * 256 + kc + ch];
            *(uint4*)&Bh[row][ch] = *(const uint4*)&bgh[(size_t)row * 256 + kc + ch];
            *(uint4*)&Bl[row][ch] = *(const uint4*)&bgl[(size_t)row * 256 + kc + ch];
        }
        __syncthreads();
        bf16x8 ah4[4], al4[4], bh4[4], bl4[4];
#pragma unroll
        for (int i = 0; i < 4; ++i) {
            ah4[i] = *(const bf16x8*)&Ah[wm + 16 * i + fr][fk];
            al4[i] = *(const bf16x8*)&Al[wm + 16 * i + fr][fk];
            bh4[i] = *(const bf16x8*)&Bh[wn + 16 * i + fr][fk];
            bl4[i] = *(const bf16x8*)&Bl[wn + 16 * i + fr][fk];
        }
#pragma unroll
        for (int i = 0; i < 4; ++i)
#pragma unroll
            for (int j = 0; j < 4; ++j) {
                acc[i][j] = __builtin_amdgcn_mfma_f32_16x16x32_bf16(ah4[i], bh4[j], acc[i][j], 0, 0, 0);
                acc[i][j] = __builtin_amdgcn_mfma_f32_16x16x32_bf16(ah4[i], bl4[j], acc[i][j], 0, 0, 0);
                acc[i][j] = __builtin_amdgcn_mfma_f32_16x16x32_bf16(al4[i], bh4[j], acc[i][j], 0, 0, 0);
            }
        __syncthreads();
    }
    // C/D layout (m89-verified): col = lane&15, row = (lane>>4)*4 + reg
    const float C2 = 2.0f * LOG2E;
    const int crow = (lane >> 4) * 4, ccol = lane & 15;
#pragma unroll
    for (int i = 0; i < 4; ++i)
#pragma unroll
        for (int j = 0; j < 4; ++j)
#pragma unroll
            for (int r = 0; r < 4; ++r)
                C[(size_t)(wm + 16 * i + crow + r) * 256 + wn + 16 * j + ccol] =
                    exp2_f(acc[i][j][r] * C2);
}

// ---------------- scores + softmax(L) + partial mean_s ----------------
// 256 blocks = (bn, s-half). 512 threads = 8 waves; wave owns 2 s; LANE = l.
// tanh fold: contribution = v_d * rcp(fma(ewx, eus, 1)); logits = -2*acc
// (the vsum constant cancels in softmax). eus/v are wave-uniform -> SGPR loads.
__global__ __launch_bounds__(512, 1) void scores_kernel(const float* __restrict__ eWx,
                                                        const float* __restrict__ eUs,
                                                        const float* __restrict__ v,
                                                        float* __restrict__ pabar)
{
    __shared__ float ewx[64][260];
    __shared__ float red[8][64];
    const int bid = blockIdx.x;
    const int bn = bid >> 1, sh = bid & 1;
    const int b = bid >> 4;
    const int tid = threadIdx.x;
    const int lane = tid & 63;                                   // = l
    const int w = __builtin_amdgcn_readfirstlane(tid >> 6);      // wave id (uniform)
    {
        const float* wxg = eWx + (size_t)bn * (Ll * Dd);
        int c = tid & 63, r0 = tid >> 6;
#pragma unroll
        for (int p = 0; p < 8; ++p) {
            int r = r0 + p * 8;
            *(float4*)&ewx[r][c * 4] = *(const float4*)&wxg[r * 256 + c * 4];
        }
    }
    __syncthreads();
    const int s0 = sh * 16 + w * 2;
    const float* eu0 = eUs + ((size_t)b * Ss + s0) * 256;        // uniform pointers
    const float* eu1 = eu0 + 256;
    float acc0 = 0.f, acc1 = 0.f;
#pragma unroll 8
    for (int q = 0; q < 64; ++q) {
        float4 w4 = *(const float4*)&ewx[lane][q * 4];           // ds_read_b128
        float4 e0 = *(const float4*)&eu0[q * 4];                 // s_load (uniform)
        float4 e1 = *(const float4*)&eu1[q * 4];
        float4 vv = *(const float4*)&v[q * 4];
        acc0 = fmaf(vv.x, rcp_f(fmaf(w4.x, e0.x, 1.0f)), acc0);
        acc0 = fmaf(vv.y, rcp_f(fmaf(w4.y, e0.y, 1.0f)), acc0);
        acc0 = fmaf(vv.z, rcp_f(fmaf(w4.z, e0.z, 1.0f)), acc0);
        acc0 = fmaf(vv.w, rcp_f(fmaf(w4.w, e0.w, 1.0f)), acc0);
        acc1 = fmaf(vv.x, rcp_f(fmaf(w4.x, e1.x, 1.0f)), acc1);
        acc1 = fmaf(vv.y, rcp_f(fmaf(w4.y, e1.y, 1.0f)), acc1);
        acc1 = fmaf(vv.z, rcp_f(fmaf(w4.z, e1.z, 1.0f)), acc1);
        acc1 = fmaf(vv.w, rcp_f(fmaf(w4.w, e1.w, 1.0f)), acc1);
    }
    float t0 = -2.0f * acc0, t1 = -2.0f * acc1;
    float e0 = exp2_f((t0 - wave_max(t0)) * LOG2E);
    float e1 = exp2_f((t1 - wave_max(t1)) * LOG2E);
    float a0 = e0 * rcp_f(wave_sum(e0));
    float a1 = e1 * rcp_f(wave_sum(e1));
    red[w][lane] = a0 + a1;
    __syncthreads();
    if (tid < 64) {
        float p = 0.f;
#pragma unroll
        for (int k = 0; k < 8; ++k) p += red[k][tid];
        pabar[(size_t)bid * 64 + tid] = p;   // partial sum over 16 s
    }
}

// ---------------- abar combine + sr[b][n][d] = sum_l abar[l]*x[bn,l,d] ----------------
__global__ __launch_bounds__(256) void sr_kernel(const float* __restrict__ pabar,
                                                 const float* __restrict__ x,
                                                 float* __restrict__ sr_out)
{
    int bn = blockIdx.x;
    int tid = threadIdx.x;
    __shared__ float abar[64];
    if (tid < 64)
        abar[tid] = (pabar[(size_t)(bn * 2) * 64 + tid] +
                     pabar[(size_t)(bn * 2 + 1) * 64 + tid]) * (1.0f / 32.0f);
    __syncthreads();
    const float* xp = x + (size_t)bn * Ll * Dd;
    float acc = 0.f;
#pragma unroll 8
    for (int l = 0; l < Ll; ++l)
        acc = fmaf(abar[l], xp[l * Dd + tid], acc);
    sr_out[(size_t)bn * Dd + tid] = acc;     // [b][n][d] since bn = b*8+n
}

// ---------------- fused gx-GEMM + sequential BiLSTM ----------------
__global__ __launch_bounds__(512) void lstm_fused(const float* __restrict__ sr,
                                                  const float* __restrict__ Wih_f,
                                                  const float* __restrict__ Wih_b,
                                                  const float* __restrict__ Whh_f,
                                                  const float* __restrict__ Whh_b,
                                                  const float* __restrict__ bih_f, const float* __restrict__ bhh_f,
                                                  const float* __restrict__ bih_b, const float* __restrict__ bhh_b,
                                                  float* __restrict__ h_out)
{
    int blk = blockIdx.x;
    int dir = blk >> 4, b = blk & 15;
    int g = threadIdx.x;
    __shared__ float s_lds[8][256];
    __shared__ float h[128], c[128], gb[512];
    {
        int nr = g >> 6, off = (g & 63) * 4;
        *(float4*)&s_lds[nr][off] = *(const float4*)&sr[((size_t)b * Nn + nr) * Dd + off];
        if (g < 128) { h[g] = 0.f; c[g] = 0.f; }
    }
    __syncthreads();
    const float* wih = ((dir == 0) ? Wih_f : Wih_b) + (size_t)g * 256;
    const float* srow[8];
#pragma unroll
    for (int tt = 0; tt < 8; ++tt) srow[tt] = s_lds[dir ? 7 - tt : tt];
    float gpre[8] = {};
#pragma unroll
    for (int kq = 0; kq < 64; ++kq) {
        float4 wv = ((const float4*)wih)[kq];
#pragma unroll
        for (int tt = 0; tt < 8; ++tt) {
            const float4 sv = *(const float4*)&srow[tt][kq * 4];
            gpre[tt] = fmaf(wv.x, sv.x, gpre[tt]);
            gpre[tt] = fmaf(wv.y, sv.y, gpre[tt]);
            gpre[tt] = fmaf(wv.z, sv.z, gpre[tt]);
            gpre[tt] = fmaf(wv.w, sv.w, gpre[tt]);
        }
    }
    const float* wr = ((dir == 0) ? Whh_f : Whh_b) + (size_t)g * 128;
    float4 w4[32];
#pragma unroll
    for (int k = 0; k < 32; ++k) w4[k] = ((const float4*)wr)[k];
    float bias = (dir == 0) ? (bih_f[g] + bhh_f[g]) : (bih_b[g] + bhh_b[g]);
    __syncthreads();
#pragma unroll
    for (int t = 0; t < Nn; ++t) {
        float a0 = gpre[t] + bias;
        float a1 = 0.f, a2 = 0.f, a3 = 0.f;
#pragma unroll
        for (int k = 0; k < 32; ++k) {
            float4 hv = *(const float4*)&h[k * 4];
            a0 = fmaf(w4[k].x, hv.x, a0);
            a1 = fmaf(w4[k].y, hv.y, a1);
            a2 = fmaf(w4[k].z, hv.z, a2);
            a3 = fmaf(w4[k].w, hv.w, a3);
        }
        float pre = (a0 + a1) + (a2 + a3);
        float act = (g < 256 || g >= 384) ? fast_sigmoid(pre) : fast_tanh(pre);
        gb[g] = act;
        __syncthreads();
        if (g < 128) {
            float i_ = gb[g], f_ = gb[128 + g], g_ = gb[256 + g], o_ = gb[384 + g];
            float cn = fmaf(f_, c[g], i_ * g_);
            float hn = o_ * fast_tanh(cn);
            c[g] = cn; h[g] = hn;
            int n = dir ? (7 - t) : t;
            h_out[(((size_t)dir * Nn + n) * Bsz + b) * Hh + g] = hn;
        }
        __syncthreads();
    }
}

// ---------------- fused self-attention scores + softmax + pool ----------------
__global__ __launch_bounds__(256) void attpool_kernel(const float* __restrict__ hbuf,
                                                      const float* __restrict__ saW,
                                                      const float* __restrict__ sab,
                                                      const float* __restrict__ sav,
                                                      float* __restrict__ out)
{
    int b = blockIdx.x;
    int e = threadIdx.x;
    __shared__ float cvec[8][260];
    __shared__ float part[8][4];
#pragma unroll
    for (int n = 0; n < 8; ++n)
        cvec[n][e] = (e < 128) ? hbuf[((size_t)n * Bsz + b) * Hh + e]
                               : hbuf[((size_t)(Nn + n) * Bsz + b) * Hh + (e - 128)];
    __syncthreads();
    const float* wrow = saW + (size_t)e * 256;
    float acc[8];
    float b0 = sab[e];
#pragma unroll
    for (int n = 0; n < 8; ++n) acc[n] = b0;
#pragma unroll 2
    for (int dq0 = 0; dq0 < 8; ++dq0) {
        float4 wq[8];
#pragma unroll
        for (int q = 0; q < 8; ++q) wq[q] = *(const float4*)&wrow[dq0 * 32 + q * 4];
#pragma unroll
        for (int q = 0; q < 8; ++q) {
#pragma unroll
            for (int n = 0; n < 8; ++n) {
                float4 cv = *(const float4*)&cvec[n][dq0 * 32 + q * 4];
                acc[n] = fmaf(wq[q].x, cv.x, acc[n]);
                acc[n] = fmaf(wq[q].y, cv.y, acc[n]);
                acc[n] = fmaf(wq[q].z, cv.z, acc[n]);
                acc[n] = fmaf(wq[q].w, cv.w, acc[n]);
            }
        }
    }
    int w = e >> 6, lane = e & 63;
    float se = sav[e];
#pragma unroll
    for (int n = 0; n < 8; ++n) {
        float t = fast_tanh(acc[n]) * se;
        t = wave_sum(t);
        if (lane == 0) part[n][w] = t;
    }
    __syncthreads();
    float av[8], mx = -1e30f;
#pragma unroll
    for (int n = 0; n < 8; ++n) {
        av[n] = part[n][0] + part[n][1] + part[n][2] + part[n][3];
        mx = fmaxf(mx, av[n]);
    }
    float sum = 0.f;
#pragma unroll
    for (int n = 0; n < 8; ++n) { av[n] = exp2_f((av[n] - mx) * LOG2E); sum += av[n]; }
    float inv = rcp_f(sum);
    float acco = 0.f;
#pragma unroll
    for (int n = 0; n < 8; ++n) acco = fmaf(av[n], cvec[n][e], acco);
    out[b * 256 + e] = acco * inv;
}

extern "C" void kernel_launch(void* const* d_in, const int* in_sizes, int n_in,
                              void* d_out, int out_size, void* d_ws, size_t ws_size,
                              hipStream_t stream) {
    const float* x     = (const float*)d_in[0];
    const float* s     = (const float*)d_in[1];
    const float* W     = (const float*)d_in[2];
    const float* U     = (const float*)d_in[3];
    const float* v     = (const float*)d_in[4];
    const float* Wih_f = (const float*)d_in[5];
    const float* Whh_f = (const float*)d_in[6];
    const float* bih_f = (const float*)d_in[7];
    const float* bhh_f = (const float*)d_in[8];
    const float* Wih_b = (const float*)d_in[9];
    const float* Whh_b = (const float*)d_in[10];
    const float* bih_b = (const float*)d_in[11];
    const float* bhh_b = (const float*)d_in[12];
    const float* saW   = (const float*)d_in[13];
    const float* sab   = (const float*)d_in[14];
    const float* sav   = (const float*)d_in[15];
    float* out = (float*)d_out;
    float* ws  = (float*)d_ws;

    float* eWx   = ws;                 // 2097152 f
    float* eUs   = eWx + 2097152;      // 131072 f
    float* pabar = eUs + 131072;       // 16384 f
    float* sr_nb = pabar + 16384;      // 32768 f [b][n][256]
    float* hbuf  = sr_nb + 32768;      // 32768 f
    unsigned short* us_base = (unsigned short*)(hbuf + 32768);
    unsigned short* xh  = us_base;             // 2097152 ushorts
    unsigned short* xl  = xh  + 2097152;
    unsigned short* sh2 = xl  + 2097152;       // 131072
    unsigned short* sl2 = sh2 + 131072;
    unsigned short* Wh  = sl2 + 131072;        // 65536
    unsigned short* Wl  = Wh  + 65536;
    unsigned short* Uh  = Wl  + 65536;
    unsigned short* Ul  = Uh  + 65536;

    hipLaunchKernelGGL(split_bf16, dim3(2304), dim3(256), 0, stream,
                       x, s, W, U, xh, xl, sh2, sl2, Wh, Wl, Uh, Ul);
    hipLaunchKernelGGL(gemm_mfma, dim3(136), dim3(256), 0, stream,
                       xh, xl, sh2, sl2, Wh, Wl, Uh, Ul, eWx, eUs);
    hipLaunchKernelGGL(scores_kernel, dim3(256), dim3(512), 0, stream, eWx, eUs, v, pabar);
    hipLaunchKernelGGL(sr_kernel, dim3(128), dim3(256), 0, stream, pabar, x, sr_nb);
    hipLaunchKernelGGL(lstm_fused, dim3(32), dim3(512), 0, stream,
                       sr_nb, Wih_f, Wih_b, Whh_f, Whh_b,
                       bih_f, bhh_f, bih_b, bhh_b, hbuf);
    hipLaunchKernelGGL(attpool_kernel, dim3(16), dim3(256), 0, stream, hbuf, saW, sab, sav, out);
}

// Round 7
// 172.991 us; speedup vs baseline: 1.2961x; 1.0025x over previous
//
#include <hip/hip_runtime.h>
#include <cstddef>

#define Bsz 16
#define Nn  8
#define Ll  64
#define Ss  32
#define Dd  256
#define Hh  128

#define LOG2E 1.4426950408889634f

typedef short bf16x8 __attribute__((ext_vector_type(8)));   // 8 bf16 = 4 VGPR
typedef float f32x4  __attribute__((ext_vector_type(4)));   // MFMA acc

__device__ __forceinline__ float rcp_f(float x)  { return __builtin_amdgcn_rcpf(x); }
__device__ __forceinline__ float exp2_f(float x) { return __builtin_amdgcn_exp2f(x); }

__device__ __forceinline__ float fast_tanh(float x) {
    return 1.0f - 2.0f * rcp_f(exp2_f(x * (2.0f * LOG2E)) + 1.0f);
}
__device__ __forceinline__ float fast_sigmoid(float x) {
    return rcp_f(1.0f + exp2_f(-x * LOG2E));
}
__device__ __forceinline__ float wave_sum(float x) {
#pragma unroll
    for (int off = 32; off > 0; off >>= 1) x += __shfl_xor(x, off, 64);
    return x;
}
__device__ __forceinline__ float wave_max(float x) {
#pragma unroll
    for (int off = 32; off > 0; off >>= 1) x = fmaxf(x, __shfl_xor(x, off, 64));
    return x;
}

// ---- truncation hi/lo split: hi = bf16-trunc(f), lo = bf16-trunc(f - hi) ----
// f - hi is exact (Sterbenz); total representation error ~2^-16 relative.
__device__ __forceinline__ void tsplit(float f, unsigned short& h, unsigned short& l) {
    unsigned u  = __builtin_bit_cast(unsigned, f);
    unsigned hb = u >> 16;
    float r = f - __builtin_bit_cast(float, hb << 16);
    h = (unsigned short)hb;
    l = (unsigned short)(__builtin_bit_cast(unsigned, r) >> 16);
}
__device__ __forceinline__ void tsplit4(float4 f, ushort4& h, ushort4& l) {
    tsplit(f.x, h.x, l.x);
    tsplit(f.y, h.y, l.y);
    tsplit(f.z, h.z, l.z);
    tsplit(f.w, h.w, l.w);
}

// ---------------- fused split + MFMA GEMM: C = exp2(C2 * A.B^T) ----------------
// A [M][256], B [rows][256] f32, K-contiguous. Staging loads f32 and splits
// in-register to hi/lo bf16 LDS tiles. Tile 128x128, 4 waves, wave = 64x64 via
// 4x4 mfma_f32_16x16x32_bf16, K-step 32. Split-3: hi.hi + hi.lo + lo.hi.
// blocks 0..127: eWx (x,W  M=8192); 128..135: eUs (s,U  M=512).
__global__ __launch_bounds__(256) void gemm_mfma(
    const float* __restrict__ x, const float* __restrict__ s,
    const float* __restrict__ W, const float* __restrict__ U,
    float* __restrict__ eWx, float* __restrict__ eUs)
{
    __shared__ unsigned short Ah[128][40], Al[128][40], Bh[128][40], Bl[128][40];
    const int tid = threadIdx.x;
    int blk = blockIdx.x;
    const float *ag, *bg; float* C;
    if (blk < 128) {
        int my = blk >> 1, nxb = blk & 1;
        ag = x + (size_t)my * 128 * 256;
        bg = W + (size_t)nxb * 128 * 256;
        C = eWx + (size_t)my * 128 * 256 + nxb * 128;
    } else {
        int b2 = blk - 128;
        int my = b2 >> 1, nxb = b2 & 1;
        ag = s + (size_t)my * 128 * 256;
        bg = U + (size_t)nxb * 128 * 256;
        C = eUs + (size_t)my * 128 * 256 + nxb * 128;
    }
    const int lane = tid & 63, w = tid >> 6;
    const int wm = (w & 1) * 64, wn = (w >> 1) * 64;
    const int fr = lane & 15, fk = (lane >> 4) * 8;
    f32x4 acc[4][4] = {};
    for (int kc = 0; kc < 256; kc += 32) {
#pragma unroll
        for (int p = 0; p < 4; ++p) {
            int f4 = p * 256 + tid;          // 1024 float4 per operand tile
            int row = f4 >> 3;               // 0..127
            int c4 = (f4 & 7) * 4;           // k offset within 32
            float4 av = *(const float4*)&ag[(size_t)row * 256 + kc + c4];
            float4 bv = *(const float4*)&bg[(size_t)row * 256 + kc + c4];
            ushort4 h4, l4;
            tsplit4(av, h4, l4);
            *(ushort4*)&Ah[row][c4] = h4;
            *(ushort4*)&Al[row][c4] = l4;
            tsplit4(bv, h4, l4);
            *(ushort4*)&Bh[row][c4] = h4;
            *(ushort4*)&Bl[row][c4] = l4;
        }
        __syncthreads();
        bf16x8 ah4[4], al4[4], bh4[4], bl4[4];
#pragma unroll
        for (int i = 0; i < 4; ++i) {
            ah4[i] = *(const bf16x8*)&Ah[wm + 16 * i + fr][fk];
            al4[i] = *(const bf16x8*)&Al[wm + 16 * i + fr][fk];
            bh4[i] = *(const bf16x8*)&Bh[wn + 16 * i + fr][fk];
            bl4[i] = *(const bf16x8*)&Bl[wn + 16 * i + fr][fk];
        }
#pragma unroll
        for (int i = 0; i < 4; ++i)
#pragma unroll
            for (int j = 0; j < 4; ++j) {
                acc[i][j] = __builtin_amdgcn_mfma_f32_16x16x32_bf16(ah4[i], bh4[j], acc[i][j], 0, 0, 0);
                acc[i][j] = __builtin_amdgcn_mfma_f32_16x16x32_bf16(ah4[i], bl4[j], acc[i][j], 0, 0, 0);
                acc[i][j] = __builtin_amdgcn_mfma_f32_16x16x32_bf16(al4[i], bh4[j], acc[i][j], 0, 0, 0);
            }
        __syncthreads();
    }
    // C/D layout (m89-verified): col = lane&15, row = (lane>>4)*4 + reg
    const float C2 = 2.0f * LOG2E;
    const int crow = (lane >> 4) * 4, ccol = lane & 15;
#pragma unroll
    for (int i = 0; i < 4; ++i)
#pragma unroll
        for (int j = 0; j < 4; ++j)
#pragma unroll
            for (int r = 0; r < 4; ++r)
                C[(size_t)(wm + 16 * i + crow + r) * 256 + wn + 16 * j + ccol] =
                    exp2_f(acc[i][j][r] * C2);
}

// ---------------- scores + softmax(L) + partial mean_s ----------------
// 256 blocks = (bn, s-half). 512 threads = 8 waves; wave owns 2 s; LANE = l.
// tanh fold: contribution = v_d * rcp(fma(ewx, eus, 1)); logits = -2*acc
// (the vsum constant cancels in softmax). eus/v are wave-uniform -> SGPR loads.
__global__ __launch_bounds__(512, 1) void scores_kernel(const float* __restrict__ eWx,
                                                        const float* __restrict__ eUs,
                                                        const float* __restrict__ v,
                                                        float* __restrict__ pabar)
{
    __shared__ float ewx[64][260];
    __shared__ float red[8][64];
    const int bid = blockIdx.x;
    const int bn = bid >> 1, sh = bid & 1;
    const int b = bid >> 4;
    const int tid = threadIdx.x;
    const int lane = tid & 63;                                   // = l
    const int w = __builtin_amdgcn_readfirstlane(tid >> 6);      // wave id (uniform)
    {
        const float* wxg = eWx + (size_t)bn * (Ll * Dd);
        int c = tid & 63, r0 = tid >> 6;
#pragma unroll
        for (int p = 0; p < 8; ++p) {
            int r = r0 + p * 8;
            *(float4*)&ewx[r][c * 4] = *(const float4*)&wxg[r * 256 + c * 4];
        }
    }
    __syncthreads();
    const int s0 = sh * 16 + w * 2;
    const float* eu0 = eUs + ((size_t)b * Ss + s0) * 256;        // uniform pointers
    const float* eu1 = eu0 + 256;
    float acc0 = 0.f, acc1 = 0.f;
#pragma unroll 8
    for (int q = 0; q < 64; ++q) {
        float4 w4 = *(const float4*)&ewx[lane][q * 4];           // ds_read_b128
        float4 e0 = *(const float4*)&eu0[q * 4];                 // s_load (uniform)
        float4 e1 = *(const float4*)&eu1[q * 4];
        float4 vv = *(const float4*)&v[q * 4];
        acc0 = fmaf(vv.x, rcp_f(fmaf(w4.x, e0.x, 1.0f)), acc0);
        acc0 = fmaf(vv.y, rcp_f(fmaf(w4.y, e0.y, 1.0f)), acc0);
        acc0 = fmaf(vv.z, rcp_f(fmaf(w4.z, e0.z, 1.0f)), acc0);
        acc0 = fmaf(vv.w, rcp_f(fmaf(w4.w, e0.w, 1.0f)), acc0);
        acc1 = fmaf(vv.x, rcp_f(fmaf(w4.x, e1.x, 1.0f)), acc1);
        acc1 = fmaf(vv.y, rcp_f(fmaf(w4.y, e1.y, 1.0f)), acc1);
        acc1 = fmaf(vv.z, rcp_f(fmaf(w4.z, e1.z, 1.0f)), acc1);
        acc1 = fmaf(vv.w, rcp_f(fmaf(w4.w, e1.w, 1.0f)), acc1);
    }
    float t0 = -2.0f * acc0, t1 = -2.0f * acc1;
    float e0 = exp2_f((t0 - wave_max(t0)) * LOG2E);
    float e1 = exp2_f((t1 - wave_max(t1)) * LOG2E);
    float a0 = e0 * rcp_f(wave_sum(e0));
    float a1 = e1 * rcp_f(wave_sum(e1));
    red[w][lane] = a0 + a1;
    __syncthreads();
    if (tid < 64) {
        float p = 0.f;
#pragma unroll
        for (int k = 0; k < 8; ++k) p += red[k][tid];
        pabar[(size_t)bid * 64 + tid] = p;   // partial sum over 16 s
    }
}

// ---------------- abar combine + sr[b][n][d] = sum_l abar[l]*x[bn,l,d] ----------------
__global__ __launch_bounds__(256) void sr_kernel(const float* __restrict__ pabar,
                                                 const float* __restrict__ x,
                                                 float* __restrict__ sr_out)
{
    int bn = blockIdx.x;
    int tid = threadIdx.x;
    __shared__ float abar[64];
    if (tid < 64)
        abar[tid] = (pabar[(size_t)(bn * 2) * 64 + tid] +
                     pabar[(size_t)(bn * 2 + 1) * 64 + tid]) * (1.0f / 32.0f);
    __syncthreads();
    const float* xp = x + (size_t)bn * Ll * Dd;
    float acc = 0.f;
#pragma unroll 8
    for (int l = 0; l < Ll; ++l)
        acc = fmaf(abar[l], xp[l * Dd + tid], acc);
    sr_out[(size_t)bn * Dd + tid] = acc;     // [b][n][d] since bn = b*8+n
}

// ---------------- fused gx-GEMM + sequential BiLSTM ----------------
__global__ __launch_bounds__(512) void lstm_fused(const float* __restrict__ sr,
                                                  const float* __restrict__ Wih_f,
                                                  const float* __restrict__ Wih_b,
                                                  const float* __restrict__ Whh_f,
                                                  const float* __restrict__ Whh_b,
                                                  const float* __restrict__ bih_f, const float* __restrict__ bhh_f,
                                                  const float* __restrict__ bih_b, const float* __restrict__ bhh_b,
                                                  float* __restrict__ h_out)
{
    int blk = blockIdx.x;
    int dir = blk >> 4, b = blk & 15;
    int g = threadIdx.x;
    __shared__ float s_lds[8][256];
    __shared__ float h[128], c[128], gb[512];
    {
        int nr = g >> 6, off = (g & 63) * 4;
        *(float4*)&s_lds[nr][off] = *(const float4*)&sr[((size_t)b * Nn + nr) * Dd + off];
        if (g < 128) { h[g] = 0.f; c[g] = 0.f; }
    }
    __syncthreads();
    const float* wih = ((dir == 0) ? Wih_f : Wih_b) + (size_t)g * 256;
    const float* srow[8];
#pragma unroll
    for (int tt = 0; tt < 8; ++tt) srow[tt] = s_lds[dir ? 7 - tt : tt];
    float gpre[8] = {};
#pragma unroll
    for (int kq = 0; kq < 64; ++kq) {
        float4 wv = ((const float4*)wih)[kq];
#pragma unroll
        for (int tt = 0; tt < 8; ++tt) {
            const float4 sv = *(const float4*)&srow[tt][kq * 4];
            gpre[tt] = fmaf(wv.x, sv.x, gpre[tt]);
            gpre[tt] = fmaf(wv.y, sv.y, gpre[tt]);
            gpre[tt] = fmaf(wv.z, sv.z, gpre[tt]);
            gpre[tt] = fmaf(wv.w, sv.w, gpre[tt]);
        }
    }
    const float* wr = ((dir == 0) ? Whh_f : Whh_b) + (size_t)g * 128;
    float4 w4[32];
#pragma unroll
    for (int k = 0; k < 32; ++k) w4[k] = ((const float4*)wr)[k];
    float bias = (dir == 0) ? (bih_f[g] + bhh_f[g]) : (bih_b[g] + bhh_b[g]);
    __syncthreads();
#pragma unroll
    for (int t = 0; t < Nn; ++t) {
        float a0 = gpre[t] + bias;
        float a1 = 0.f, a2 = 0.f, a3 = 0.f;
#pragma unroll
        for (int k = 0; k < 32; ++k) {
            float4 hv = *(const float4*)&h[k * 4];
            a0 = fmaf(w4[k].x, hv.x, a0);
            a1 = fmaf(w4[k].y, hv.y, a1);
            a2 = fmaf(w4[k].z, hv.z, a2);
            a3 = fmaf(w4[k].w, hv.w, a3);
        }
        float pre = (a0 + a1) + (a2 + a3);
        float act = (g < 256 || g >= 384) ? fast_sigmoid(pre) : fast_tanh(pre);
        gb[g] = act;
        __syncthreads();
        if (g < 128) {
            float i_ = gb[g], f_ = gb[128 + g], g_ = gb[256 + g], o_ = gb[384 + g];
            float cn = fmaf(f_, c[g], i_ * g_);
            float hn = o_ * fast_tanh(cn);
            c[g] = cn; h[g] = hn;
            int n = dir ? (7 - t) : t;
            h_out[(((size_t)dir * Nn + n) * Bsz + b) * Hh + g] = hn;
        }
        __syncthreads();
    }
}

// ---------------- fused self-attention scores + softmax + pool ----------------
__global__ __launch_bounds__(256) void attpool_kernel(const float* __restrict__ hbuf,
                                                      const float* __restrict__ saW,
                                                      const float* __restrict__ sab,
                                                      const float* __restrict__ sav,
                                                      float* __restrict__ out)
{
    int b = blockIdx.x;
    int e = threadIdx.x;
    __shared__ float cvec[8][260];
    __shared__ float part[8][4];
#pragma unroll
    for (int n = 0; n < 8; ++n)
        cvec[n][e] = (e < 128) ? hbuf[((size_t)n * Bsz + b) * Hh + e]
                               : hbuf[((size_t)(Nn + n) * Bsz + b) * Hh + (e - 128)];
    __syncthreads();
    const float* wrow = saW + (size_t)e * 256;
    float acc[8];
    float b0 = sab[e];
#pragma unroll
    for (int n = 0; n < 8; ++n) acc[n] = b0;
#pragma unroll 2
    for (int dq0 = 0; dq0 < 8; ++dq0) {
        float4 wq[8];
#pragma unroll
        for (int q = 0; q < 8; ++q) wq[q] = *(const float4*)&wrow[dq0 * 32 + q * 4];
#pragma unroll
        for (int q = 0; q < 8; ++q) {
#pragma unroll
            for (int n = 0; n < 8; ++n) {
                float4 cv = *(const float4*)&cvec[n][dq0 * 32 + q * 4];
                acc[n] = fmaf(wq[q].x, cv.x, acc[n]);
                acc[n] = fmaf(wq[q].y, cv.y, acc[n]);
                acc[n] = fmaf(wq[q].z, cv.z, acc[n]);
                acc[n] = fmaf(wq[q].w, cv.w, acc[n]);
            }
        }
    }
    int w = e >> 6, lane = e & 63;
    float se = sav[e];
#pragma unroll
    for (int n = 0; n < 8; ++n) {
        float t = fast_tanh(acc[n]) * se;
        t = wave_sum(t);
        if (lane == 0) part[n][w] = t;
    }
    __syncthreads();
    float av[8], mx = -1e30f;
#pragma unroll
    for (int n = 0; n < 8; ++n) {
        av[n] = part[n][0] + part[n][1] + part[n][2] + part[n][3];
        mx = fmaxf(mx, av[n]);
    }
    float sum = 0.f;
#pragma unroll
    for (int n = 0; n < 8; ++n) { av[n] = exp2_f((av[n] - mx) * LOG2E); sum += av[n]; }
    float inv = rcp_f(sum);
    float acco = 0.f;
#pragma unroll
    for (int n = 0; n < 8; ++n) acco = fmaf(av[n], cvec[n][e], acco);
    out[b * 256 + e] = acco * inv;
}

extern "C" void kernel_launch(void* const* d_in, const int* in_sizes, int n_in,
                              void* d_out, int out_size, void* d_ws, size_t ws_size,
                              hipStream_t stream) {
    const float* x     = (const float*)d_in[0];
    const float* s     = (const float*)d_in[1];
    const float* W     = (const float*)d_in[2];
    const float* U     = (const float*)d_in[3];
    const float* v     = (const float*)d_in[4];
    const float* Wih_f = (const float*)d_in[5];
    const float* Whh_f = (const float*)d_in[6];
    const float* bih_f = (const float*)d_in[7];
    const float* bhh_f = (const float*)d_in[8];
    const float* Wih_b = (const float*)d_in[9];
    const float* Whh_b = (const float*)d_in[10];
    const float* bih_b = (const float*)d_in[11];
    const float* bhh_b = (const float*)d_in[12];
    const float* saW   = (const float*)d_in[13];
    const float* sab   = (const float*)d_in[14];
    const float* sav   = (const float*)d_in[15];
    float* out = (float*)d_out;
    float* ws  = (float*)d_ws;

    float* eWx   = ws;                 // 2097152 f
    float* eUs   = eWx + 2097152;      // 131072 f
    float* pabar = eUs + 131072;       // 16384 f
    float* sr_nb = pabar + 16384;      // 32768 f [b][n][256]
    float* hbuf  = sr_nb + 32768;      // 32768 f

    hipLaunchKernelGGL(gemm_mfma, dim3(136), dim3(256), 0, stream,
                       x, s, W, U, eWx, eUs);
    hipLaunchKernelGGL(scores_kernel, dim3(256), dim3(512), 0, stream, eWx, eUs, v, pabar);
    hipLaunchKernelGGL(sr_kernel, dim3(128), dim3(256), 0, stream, pabar, x, sr_nb);
    hipLaunchKernelGGL(lstm_fused, dim3(32), dim3(512), 0, stream,
                       sr_nb, Wih_f, Wih_b, Whh_f, Whh_b,
                       bih_f, bhh_f, bih_b, bhh_b, hbuf);
    hipLaunchKernelGGL(attpool_kernel, dim3(16), dim3(256), 0, stream, hbuf, saW, sab, sav, out);
}